// Round 7
// baseline (389.463 us; speedup 1.0000x reference)
//
#include <hip/hip_runtime.h>
#include <stdint.h>

// LmHead: RMSNorm(8x4096) -> logits = h @ W^T (W: 32000x4096 f32) -> argmax per row.
// Memory-bound: W is 524 MB (> L3) -> pure HBM read stream, floor ~82us.
// R4 (126us, BEST): reg h+W ping-pong, counted vmcnt. Latency-marginal:
//   coverage = waves/SIMD x phase ~= 900cyc ~= HBM latency, zero slack.
// R5 (168us): depth-2 via FULL 16-phase unroll -> spills/scheduler chaos.
// R3 (150us) & R6 (295us): LDS-h puts ~120cyc lgkmcnt on the per-phase critical
//   path (compiler didn't pipeline my ds_read->FMA macro). h stays in VGPRs.
// R7: R4 structure + W prefetch depth 2 done RIGHT: 6-phase rolled body
//   (c in {0,6} -> static w0/w1/w2 names, no full unroll), h single-buffer
//   loaded at phase top (saves 32 VGPR; L2 latency hidden by 3-wave rotation),
//   launch_bounds(256,3) (<=168 VGPR, no spill). Coverage ~2x900 >> latency.

#define D 4096
#define BATCH 8
#define VOCAB 32000
#define VT 4                 // vocab rows per wave
#define NBLK 2000            // 4 waves/block -> 8000 waves, exactly 1 group per wave
#define EPS 1e-6f

typedef unsigned long long u64;
typedef float f32x4 __attribute__((ext_vector_type(4)));

// ---------------- Kernel A: RMSNorm -> h in workspace ----------------
__global__ __launch_bounds__(256) void rmsnorm_k(const float* __restrict__ x,
                                                 const float* __restrict__ g,
                                                 float* __restrict__ h) {
    const int b = blockIdx.x;
    const int t = threadIdx.x;
    const int wave = t >> 6, lane = t & 63;
    const float* xr = x + b * D;

    f32x4 xv[4];
    float s = 0.f;
#pragma unroll
    for (int i = 0; i < 4; ++i) {
        xv[i] = *(const f32x4*)(xr + i * 1024 + t * 4);
        s += xv[i].x * xv[i].x + xv[i].y * xv[i].y + xv[i].z * xv[i].z + xv[i].w * xv[i].w;
    }
#pragma unroll
    for (int m = 1; m < 64; m <<= 1) s += __shfl_xor(s, m, 64);

    __shared__ float wsum[4];
    if (lane == 0) wsum[wave] = s;
    __syncthreads();
    const float tot = wsum[0] + wsum[1] + wsum[2] + wsum[3];
    const float rs = rsqrtf(tot * (1.f / (float)D) + EPS);

#pragma unroll
    for (int i = 0; i < 4; ++i) {
        const int d = i * 1024 + t * 4;
        const f32x4 gv = *(const f32x4*)(g + d);
        f32x4 o;
        o.x = xv[i].x * rs * gv.x;
        o.y = xv[i].y * rs * gv.y;
        o.z = xv[i].z * rs * gv.z;
        o.w = xv[i].w * rs * gv.w;
        *(f32x4*)(h + b * D + d) = o;
    }
}

// ---- Kernel B: W triple-buffer depth-2 prefetch, h single-buffer, argmax ----
__global__ __launch_bounds__(256, 3) void gemv_argmax_k(const float* __restrict__ W,
                                                        const float* __restrict__ h,
                                                        u64* __restrict__ partial) {
    const int lane = threadIdx.x & 63;
    const int wave = threadIdx.x >> 6;
    const int grp = blockIdx.x * 4 + wave;       // [0, 8000)
    const int v0 = grp * VT;
    const float* Wb = W + (size_t)v0 * D;
    const int dl = lane * 4;

    float acc[32];
#pragma unroll
    for (int i = 0; i < 32; ++i) acc[i] = 0.f;

    f32x4 hb[8];              // h single buffer (L2-hot, loaded at phase top)
    f32x4 w0[VT], w1[VT], w2[VT];  // W triple buffer, prefetch distance 2

#define LOADH(c)                                                               \
    {                                                                          \
        const int _d = (c) * 256 + dl;                                         \
        _Pragma("unroll")                                                      \
        for (int b = 0; b < 8; ++b)                                            \
            hb[b] = *(const f32x4*)(h + b * D + _d);                           \
    }

#define LOADW(BUF, c)                                                          \
    {                                                                          \
        const int _d = (c) * 256 + dl;                                         \
        _Pragma("unroll")                                                      \
        for (int vi = 0; vi < VT; ++vi)                                        \
            BUF[vi] = __builtin_nontemporal_load((const f32x4*)(Wb + vi * D + _d)); \
    }

#define COMPUTE(WBUF)                                                          \
    {                                                                          \
        _Pragma("unroll")                                                      \
        for (int b = 0; b < 8; ++b) {                                          \
            _Pragma("unroll")                                                  \
            for (int vi = 0; vi < VT; ++vi)                                    \
                acc[b * VT + vi] += WBUF[vi].x * hb[b].x + WBUF[vi].y * hb[b].y + \
                                    WBUF[vi].z * hb[b].z + WBUF[vi].w * hb[b].w;  \
        }                                                                      \
    }

// phase: load h(c) [8, older], prefetch W(c+2) [4, younger], compute c.
// compute waits counted vmcnt(4) for h(c); W(c) is 2 phases old -> covered.
#define PHASE(WUSE, WLOAD, c)  LOADH(c) LOADW(WLOAD, (c) + 2) COMPUTE(WUSE)
#define PHASE_NOLOAD(WUSE, c)  LOADH(c) COMPUTE(WUSE)

    // prologue: W(0), W(1) in flight (oldest first)
    LOADW(w0, 0)
    LOADW(w1, 1)

    // main: 6-phase body, c in {0, 6}; buffer names static (c % 6 == 0)
#pragma unroll 1
    for (int c = 0; c < 12; c += 6) {
        PHASE(w0, w2, c + 0)
        PHASE(w1, w0, c + 1)
        PHASE(w2, w1, c + 2)
        PHASE(w0, w2, c + 3)
        PHASE(w1, w0, c + 4)
        PHASE(w2, w1, c + 5)
    }
    // peeled tail: chunks 12..15 (W loads for 14,15 only)
    PHASE(w0, w2, 12)
    PHASE(w1, w0, 13)
    PHASE_NOLOAD(w2, 14)
    PHASE_NOLOAD(w0, 15)
#undef LOADH
#undef LOADW
#undef COMPUTE
#undef PHASE
#undef PHASE_NOLOAD

    // Butterfly: 32 partials across 64 lanes -> lane l holds total for
    // j = l&31 (b = j>>2, vi = j&3). All indices compile-time.
#pragma unroll
    for (int s = 0; s < 5; ++s) {
        const int m = 1 << s;
        const bool bit = (lane & m) != 0;
#pragma unroll
        for (int u = 0; u < (32 >> (s + 1)); ++u) {
            const float a = acc[2 * u];
            const float c2 = acc[2 * u + 1];
            const float keep = bit ? c2 : a;
            const float send = bit ? a : c2;
            acc[u] = keep + __shfl_xor(send, m, 64);
        }
    }
    const float logit = acc[0] + __shfl_xor(acc[0], 32, 64);  // fold dup halves

    const int vidx = v0 + (lane & 3);
    const uint32_t fb = __float_as_uint(logit);
    const uint32_t key = (fb & 0x80000000u) ? ~fb : (fb | 0x80000000u);
    u64 best = ((u64)key << 32) | (uint32_t)(~(uint32_t)vidx);

    // merge across vi (bits 0,1); halves are duplicates after the fold
#pragma unroll
    for (int m = 1; m <= 2; m <<= 1) {
        const u64 o = __shfl_xor(best, m, 64);
        if (o > best) best = o;
    }
    {
        const u64 o = __shfl_xor(best, 32, 64);
        if (o > best) best = o;
    }

    __shared__ u64 lb[4][8];
    if (lane < 32 && (lane & 3) == 0) lb[wave][lane >> 2] = best;
    __syncthreads();
    if (threadIdx.x < 8) {
        const u64 m0 = lb[0][threadIdx.x], m1 = lb[1][threadIdx.x];
        const u64 m2 = lb[2][threadIdx.x], m3 = lb[3][threadIdx.x];
        const u64 a = m0 > m1 ? m0 : m1;
        const u64 b2 = m2 > m3 ? m2 : m3;
        partial[(size_t)blockIdx.x * 8 + threadIdx.x] = a > b2 ? a : b2;
    }
}

// ---------------- Kernel C: final argmax over block partials ----------------
__global__ __launch_bounds__(512) void finalize_k(const u64* __restrict__ partial,
                                                  int* __restrict__ out, int nblk) {
    const int b = threadIdx.x >> 6;   // one wave per batch row
    const int lane = threadIdx.x & 63;
    u64 best = 0ull;
    for (int p = lane; p < nblk; p += 64) {
        const u64 x = partial[(size_t)p * 8 + b];
        if (x > best) best = x;
    }
#pragma unroll
    for (int m = 1; m < 64; m <<= 1) {
        const u64 o = __shfl_xor(best, m, 64);
        if (o > best) best = o;
    }
    if (lane == 0) out[b] = (int)(~(uint32_t)best);
}

extern "C" void kernel_launch(void* const* d_in, const int* in_sizes, int n_in,
                              void* d_out, int out_size, void* d_ws, size_t ws_size,
                              hipStream_t stream) {
    const float* x = (const float*)d_in[0]; // hidden_states [8,4096]
    const float* g = (const float*)d_in[1]; // norm_weight [4096]
    const float* W = (const float*)d_in[2]; // lm_head_weight [32000,4096]
    int* out = (int*)d_out;                 // [8] int32 token ids

    float* h = (float*)d_ws;                                        // 128 KB
    u64* partial = (u64*)((char*)d_ws + BATCH * D * sizeof(float)); // 2000*8*8B

    rmsnorm_k<<<BATCH, 256, 0, stream>>>(x, g, h);
    gemv_argmax_k<<<NBLK, 256, 0, stream>>>(W, h, partial);
    finalize_k<<<1, 512, 0, stream>>>(partial, out, NBLK);
}

// Round 8
// 173.901 us; speedup vs baseline: 2.2396x; 2.2396x over previous
//
#include <hip/hip_runtime.h>
#include <stdint.h>

// LmHead: RMSNorm(8x4096) -> logits = h @ W^T (W: 32000x4096 f32) -> argmax per row.
// Memory-bound: W is 524 MB (> L3) -> pure HBM read stream, floor ~82us.
// R4 (126us, BEST): reg h+W ping-pong, counted vmcnt, NO launch_bounds min-arg.
//   W issue-to-use = 1 phase ~= 900cyc ~= HBM latency: latency-MARGINAL.
// R5/R7 (168/389us): __launch_bounds__(256,3) made the allocator SPILL the
//   buffers (R7: VGPR_Count=84, WRITE_SIZE~646MB of scratch traffic, 1.5TB/s).
//   NEVER cap occupancy under big reg arrays. Also R7 issued H(c) for
//   same-phase use: the vmcnt wait on h forced all older W prefetches to
//   retire (in-order queue) -> depth-2 pipeline drained every phase.
// R8: R4 structure, plain __launch_bounds__(256), depth-2 W done right:
//   phase(c) = LOADH(c+1), LOADW(c+2), COMPUTE(c). Waited-on loads are always
//   the oldest outstanding; h 1 phase ahead (L2 ~250cyc), W 2 phases ahead
//   (~1800 wall-cyc >> 900 HBM latency). 6-phase rolled body -> static names.

#define D 4096
#define BATCH 8
#define VOCAB 32000
#define VT 4                 // vocab rows per wave
#define NBLK 2000            // 4 waves/block -> 8000 waves, exactly 1 group per wave
#define EPS 1e-6f

typedef unsigned long long u64;
typedef float f32x4 __attribute__((ext_vector_type(4)));

// ---------------- Kernel A: RMSNorm -> h in workspace ----------------
__global__ __launch_bounds__(256) void rmsnorm_k(const float* __restrict__ x,
                                                 const float* __restrict__ g,
                                                 float* __restrict__ h) {
    const int b = blockIdx.x;
    const int t = threadIdx.x;
    const int wave = t >> 6, lane = t & 63;
    const float* xr = x + b * D;

    f32x4 xv[4];
    float s = 0.f;
#pragma unroll
    for (int i = 0; i < 4; ++i) {
        xv[i] = *(const f32x4*)(xr + i * 1024 + t * 4);
        s += xv[i].x * xv[i].x + xv[i].y * xv[i].y + xv[i].z * xv[i].z + xv[i].w * xv[i].w;
    }
#pragma unroll
    for (int m = 1; m < 64; m <<= 1) s += __shfl_xor(s, m, 64);

    __shared__ float wsum[4];
    if (lane == 0) wsum[wave] = s;
    __syncthreads();
    const float tot = wsum[0] + wsum[1] + wsum[2] + wsum[3];
    const float rs = rsqrtf(tot * (1.f / (float)D) + EPS);

#pragma unroll
    for (int i = 0; i < 4; ++i) {
        const int d = i * 1024 + t * 4;
        const f32x4 gv = *(const f32x4*)(g + d);
        f32x4 o;
        o.x = xv[i].x * rs * gv.x;
        o.y = xv[i].y * rs * gv.y;
        o.z = xv[i].z * rs * gv.z;
        o.w = xv[i].w * rs * gv.w;
        *(f32x4*)(h + b * D + d) = o;
    }
}

// ---- Kernel B: h dbuf (1 ahead) + W triple buf (2 ahead), counted vmcnt ----
__global__ __launch_bounds__(256) void gemv_argmax_k(const float* __restrict__ W,
                                                     const float* __restrict__ h,
                                                     u64* __restrict__ partial) {
    const int lane = threadIdx.x & 63;
    const int wave = threadIdx.x >> 6;
    const int grp = blockIdx.x * 4 + wave;       // [0, 8000)
    const int v0 = grp * VT;
    const float* Wb = W + (size_t)v0 * D;
    const int dl = lane * 4;

    float acc[32];
#pragma unroll
    for (int i = 0; i < 32; ++i) acc[i] = 0.f;

    f32x4 hA[8], hB[8];            // h ping-pong, loaded 1 phase ahead (L2-hot)
    f32x4 w0[VT], w1[VT], w2[VT];  // W triple buffer, loaded 2 phases ahead

#define LOADH(HB, c)                                                           \
    {                                                                          \
        const int _d = (c) * 256 + dl;                                         \
        _Pragma("unroll")                                                      \
        for (int b = 0; b < 8; ++b)                                            \
            HB[b] = *(const f32x4*)(h + b * D + _d);                           \
    }

#define LOADW(BUF, c)                                                          \
    {                                                                          \
        const int _d = (c) * 256 + dl;                                         \
        _Pragma("unroll")                                                      \
        for (int vi = 0; vi < VT; ++vi)                                        \
            BUF[vi] = __builtin_nontemporal_load((const f32x4*)(Wb + vi * D + _d)); \
    }

#define COMPUTE(HB, WBUF)                                                      \
    {                                                                          \
        _Pragma("unroll")                                                      \
        for (int b = 0; b < 8; ++b) {                                          \
            _Pragma("unroll")                                                  \
            for (int vi = 0; vi < VT; ++vi)                                    \
                acc[b * VT + vi] += WBUF[vi].x * HB[b].x + WBUF[vi].y * HB[b].y + \
                                    WBUF[vi].z * HB[b].z + WBUF[vi].w * HB[b].w;  \
        }                                                                      \
    }

    // prologue (issue order = retirement order = use order):
    LOADH(hA, 0)        // h(0) -> hA
    LOADW(w0, 0)        // W(0)
    LOADW(w1, 1)        // W(1)

    // phase(c): LOADH(c+1), LOADW(c+2), COMPUTE(c).
    // At COMPUTE(c), h(c) and W(c) are the oldest outstanding; the 16 younger
    // loads (W(c+1), h(c+1), W(c+2)) stay in flight -> counted vmcnt, no drain.
#pragma unroll 1
    for (int c = 0; c < 12; c += 6) {
        LOADH(hB, c + 1) LOADW(w2, c + 2) COMPUTE(hA, w0)
        LOADH(hA, c + 2) LOADW(w0, c + 3) COMPUTE(hB, w1)
        LOADH(hB, c + 3) LOADW(w1, c + 4) COMPUTE(hA, w2)
        LOADH(hA, c + 4) LOADW(w2, c + 5) COMPUTE(hB, w0)
        LOADH(hB, c + 5) LOADW(w0, c + 6) COMPUTE(hA, w1)
        LOADH(hA, c + 6) LOADW(w1, c + 7) COMPUTE(hB, w2)
    }
    // tail: chunks 12..15 (valid loads only)
    LOADH(hB, 13) LOADW(w2, 14) COMPUTE(hA, w0)   // c=12
    LOADH(hA, 14) LOADW(w0, 15) COMPUTE(hB, w1)   // c=13
    LOADH(hB, 15)               COMPUTE(hA, w2)   // c=14
                                COMPUTE(hB, w0)   // c=15
#undef LOADH
#undef LOADW
#undef COMPUTE

    // Butterfly: 32 partials across 64 lanes -> lane l holds total for
    // j = l&31 (b = j>>2, vi = j&3). All indices compile-time.
#pragma unroll
    for (int s = 0; s < 5; ++s) {
        const int m = 1 << s;
        const bool bit = (lane & m) != 0;
#pragma unroll
        for (int u = 0; u < (32 >> (s + 1)); ++u) {
            const float a = acc[2 * u];
            const float c2 = acc[2 * u + 1];
            const float keep = bit ? c2 : a;
            const float send = bit ? a : c2;
            acc[u] = keep + __shfl_xor(send, m, 64);
        }
    }
    const float logit = acc[0] + __shfl_xor(acc[0], 32, 64);  // fold dup halves

    const int vidx = v0 + (lane & 3);
    const uint32_t fb = __float_as_uint(logit);
    const uint32_t key = (fb & 0x80000000u) ? ~fb : (fb | 0x80000000u);
    u64 best = ((u64)key << 32) | (uint32_t)(~(uint32_t)vidx);

    // merge across vi (bits 0,1); halves are duplicates after the fold
#pragma unroll
    for (int m = 1; m <= 2; m <<= 1) {
        const u64 o = __shfl_xor(best, m, 64);
        if (o > best) best = o;
    }
    {
        const u64 o = __shfl_xor(best, 32, 64);
        if (o > best) best = o;
    }

    __shared__ u64 lb[4][8];
    if (lane < 32 && (lane & 3) == 0) lb[wave][lane >> 2] = best;
    __syncthreads();
    if (threadIdx.x < 8) {
        const u64 m0 = lb[0][threadIdx.x], m1 = lb[1][threadIdx.x];
        const u64 m2 = lb[2][threadIdx.x], m3 = lb[3][threadIdx.x];
        const u64 a = m0 > m1 ? m0 : m1;
        const u64 b2 = m2 > m3 ? m2 : m3;
        partial[(size_t)blockIdx.x * 8 + threadIdx.x] = a > b2 ? a : b2;
    }
}

// ---------------- Kernel C: final argmax over block partials ----------------
__global__ __launch_bounds__(512) void finalize_k(const u64* __restrict__ partial,
                                                  int* __restrict__ out, int nblk) {
    const int b = threadIdx.x >> 6;   // one wave per batch row
    const int lane = threadIdx.x & 63;
    u64 best = 0ull;
    for (int p = lane; p < nblk; p += 64) {
        const u64 x = partial[(size_t)p * 8 + b];
        if (x > best) best = x;
    }
#pragma unroll
    for (int m = 1; m < 64; m <<= 1) {
        const u64 o = __shfl_xor(best, m, 64);
        if (o > best) best = o;
    }
    if (lane == 0) out[b] = (int)(~(uint32_t)best);
}

extern "C" void kernel_launch(void* const* d_in, const int* in_sizes, int n_in,
                              void* d_out, int out_size, void* d_ws, size_t ws_size,
                              hipStream_t stream) {
    const float* x = (const float*)d_in[0]; // hidden_states [8,4096]
    const float* g = (const float*)d_in[1]; // norm_weight [4096]
    const float* W = (const float*)d_in[2]; // lm_head_weight [32000,4096]
    int* out = (int*)d_out;                 // [8] int32 token ids

    float* h = (float*)d_ws;                                        // 128 KB
    u64* partial = (u64*)((char*)d_ws + BATCH * D * sizeof(float)); // 2000*8*8B

    rmsnorm_k<<<BATCH, 256, 0, stream>>>(x, g, h);
    gemv_argmax_k<<<NBLK, 256, 0, stream>>>(W, h, partial);
    finalize_k<<<1, 512, 0, stream>>>(partial, out, NBLK);
}

// Round 9
// 133.778 us; speedup vs baseline: 2.9113x; 1.2999x over previous
//
#include <hip/hip_runtime.h>
#include <stdint.h>

// LmHead: RMSNorm(8x4096) -> logits = h @ W^T (W: 32000x4096 f32) -> argmax per row.
// Memory-bound: W is 524 MB -> HBM read stream, floor ~82us (ignoring L3).
// R4 (126us, BEST): reg h+W ping-pong, counted vmcnt, plain launch_bounds(256).
// R5/R7/R8 (168/389/174us): every depth-2 / LDS / launch-bounds variant lost --
//   allocator spills (R7: VGPR=84 + 646MB scratch WRITE) or occupancy cliffs.
// R9 = R4 with ONE change: W loads are PLAIN (not nontemporal). All prior
//   rounds bypassed L2/L3 allocation with nt. The harness times graph REPLAYS
//   of the same 524MB W stream; the 256MB Infinity Cache with non-LRU
//   replacement should serve ~C/S ~ 49% of it on replay. nt forcibly discarded
//   that reuse and paid full HBM latency per request.

#define D 4096
#define BATCH 8
#define VOCAB 32000
#define VT 4                 // vocab rows per wave
#define NBLK 2000            // 4 waves/block -> 8000 waves, exactly 1 group per wave
#define EPS 1e-6f

typedef unsigned long long u64;
typedef float f32x4 __attribute__((ext_vector_type(4)));

// ---------------- Kernel A: RMSNorm -> h in workspace ----------------
__global__ __launch_bounds__(256) void rmsnorm_k(const float* __restrict__ x,
                                                 const float* __restrict__ g,
                                                 float* __restrict__ h) {
    const int b = blockIdx.x;
    const int t = threadIdx.x;
    const int wave = t >> 6, lane = t & 63;
    const float* xr = x + b * D;

    f32x4 xv[4];
    float s = 0.f;
#pragma unroll
    for (int i = 0; i < 4; ++i) {
        xv[i] = *(const f32x4*)(xr + i * 1024 + t * 4);
        s += xv[i].x * xv[i].x + xv[i].y * xv[i].y + xv[i].z * xv[i].z + xv[i].w * xv[i].w;
    }
#pragma unroll
    for (int m = 1; m < 64; m <<= 1) s += __shfl_xor(s, m, 64);

    __shared__ float wsum[4];
    if (lane == 0) wsum[wave] = s;
    __syncthreads();
    const float tot = wsum[0] + wsum[1] + wsum[2] + wsum[3];
    const float rs = rsqrtf(tot * (1.f / (float)D) + EPS);

#pragma unroll
    for (int i = 0; i < 4; ++i) {
        const int d = i * 1024 + t * 4;
        const f32x4 gv = *(const f32x4*)(g + d);
        f32x4 o;
        o.x = xv[i].x * rs * gv.x;
        o.y = xv[i].y * rs * gv.y;
        o.z = xv[i].z * rs * gv.z;
        o.w = xv[i].w * rs * gv.w;
        *(f32x4*)(h + b * D + d) = o;
    }
}

// ---- Kernel B: reg-dbuf (h AND W), counted-vmcnt GEMV + packed argmax ----
__global__ __launch_bounds__(256) void gemv_argmax_k(const float* __restrict__ W,
                                                     const float* __restrict__ h,
                                                     u64* __restrict__ partial) {
    const int lane = threadIdx.x & 63;
    const int wave = threadIdx.x >> 6;
    const int grp = blockIdx.x * 4 + wave;       // [0, 8000)
    const int v0 = grp * VT;
    const float* Wb = W + (size_t)v0 * D;
    const int dl = lane * 4;

    float acc[32];
#pragma unroll
    for (int i = 0; i < 32; ++i) acc[i] = 0.f;

    f32x4 wA[VT], wB[VT];      // W double-buffer (PLAIN loads: L2/L3 cacheable)
    f32x4 hA[8], hB[8];        // h double-buffer (L2-hot)

#define LOADH(HB, c)                                                           \
    {                                                                          \
        const int _d = (c) * 256 + dl;                                         \
        _Pragma("unroll")                                                      \
        for (int b = 0; b < 8; ++b)                                            \
            HB[b] = *(const f32x4*)(h + b * D + _d);                           \
    }

#define LOADW(BUF, c)                                                          \
    {                                                                          \
        const int _d = (c) * 256 + dl;                                         \
        _Pragma("unroll")                                                      \
        for (int vi = 0; vi < VT; ++vi)                                        \
            BUF[vi] = *(const f32x4*)(Wb + vi * D + _d);                       \
    }

#define COMPUTE(HB, WBUF)                                                      \
    {                                                                          \
        _Pragma("unroll")                                                      \
        for (int b = 0; b < 8; ++b) {                                          \
            _Pragma("unroll")                                                  \
            for (int vi = 0; vi < VT; ++vi)                                    \
                acc[b * VT + vi] += WBUF[vi].x * HB[b].x + WBUF[vi].y * HB[b].y + \
                                    WBUF[vi].z * HB[b].z + WBUF[vi].w * HB[b].w;  \
        }                                                                      \
    }

    // prologue: fill A with chunk 0
    LOADH(hA, 0)
    LOADW(wA, 0)
    // steady state: issue next chunk's 12 loads, then compute current (oldest)
#pragma unroll 1
    for (int c = 0; c <= 12; c += 2) {
        LOADH(hB, c + 1)
        LOADW(wB, c + 1)
        COMPUTE(hA, wA)        // waits counted vmcnt — queue never drains
        LOADH(hA, c + 2)       // c+2 <= 14
        LOADW(wA, c + 2)
        COMPUTE(hB, wB)
    }
    // loop exit: computed through chunk 13; chunk 14 resident in A
    LOADH(hB, 15)
    LOADW(wB, 15)
    COMPUTE(hA, wA)
    COMPUTE(hB, wB)
#undef LOADH
#undef LOADW
#undef COMPUTE

    // Butterfly: 32 partials across 64 lanes -> lane l holds total for
    // j = l&31 (b = j>>2, vi = j&3). All indices compile-time.
#pragma unroll
    for (int s = 0; s < 5; ++s) {
        const int m = 1 << s;
        const bool bit = (lane & m) != 0;
#pragma unroll
        for (int u = 0; u < (32 >> (s + 1)); ++u) {
            const float a = acc[2 * u];
            const float c2 = acc[2 * u + 1];
            const float keep = bit ? c2 : a;
            const float send = bit ? a : c2;
            acc[u] = keep + __shfl_xor(send, m, 64);
        }
    }
    const float logit = acc[0] + __shfl_xor(acc[0], 32, 64);  // fold dup halves

    const int vidx = v0 + (lane & 3);
    const uint32_t fb = __float_as_uint(logit);
    const uint32_t key = (fb & 0x80000000u) ? ~fb : (fb | 0x80000000u);
    u64 best = ((u64)key << 32) | (uint32_t)(~(uint32_t)vidx);

    // merge across vi (bits 0,1); halves are duplicates after the fold
#pragma unroll
    for (int m = 1; m <= 2; m <<= 1) {
        const u64 o = __shfl_xor(best, m, 64);
        if (o > best) best = o;
    }
    {
        const u64 o = __shfl_xor(best, 32, 64);
        if (o > best) best = o;
    }

    __shared__ u64 lb[4][8];
    if (lane < 32 && (lane & 3) == 0) lb[wave][lane >> 2] = best;
    __syncthreads();
    if (threadIdx.x < 8) {
        const u64 m0 = lb[0][threadIdx.x], m1 = lb[1][threadIdx.x];
        const u64 m2 = lb[2][threadIdx.x], m3 = lb[3][threadIdx.x];
        const u64 a = m0 > m1 ? m0 : m1;
        const u64 b2 = m2 > m3 ? m2 : m3;
        partial[(size_t)blockIdx.x * 8 + threadIdx.x] = a > b2 ? a : b2;
    }
}

// ---------------- Kernel C: final argmax over block partials ----------------
__global__ __launch_bounds__(512) void finalize_k(const u64* __restrict__ partial,
                                                  int* __restrict__ out, int nblk) {
    const int b = threadIdx.x >> 6;   // one wave per batch row
    const int lane = threadIdx.x & 63;
    u64 best = 0ull;
    for (int p = lane; p < nblk; p += 64) {
        const u64 x = partial[(size_t)p * 8 + b];
        if (x > best) best = x;
    }
#pragma unroll
    for (int m = 1; m < 64; m <<= 1) {
        const u64 o = __shfl_xor(best, m, 64);
        if (o > best) best = o;
    }
    if (lane == 0) out[b] = (int)(~(uint32_t)best);
}

extern "C" void kernel_launch(void* const* d_in, const int* in_sizes, int n_in,
                              void* d_out, int out_size, void* d_ws, size_t ws_size,
                              hipStream_t stream) {
    const float* x = (const float*)d_in[0]; // hidden_states [8,4096]
    const float* g = (const float*)d_in[1]; // norm_weight [4096]
    const float* W = (const float*)d_in[2]; // lm_head_weight [32000,4096]
    int* out = (int*)d_out;                 // [8] int32 token ids

    float* h = (float*)d_ws;                                        // 128 KB
    u64* partial = (u64*)((char*)d_ws + BATCH * D * sizeof(float)); // 2000*8*8B

    rmsnorm_k<<<BATCH, 256, 0, stream>>>(x, g, h);
    gemv_argmax_k<<<NBLK, 256, 0, stream>>>(W, h, partial);
    finalize_k<<<1, 512, 0, stream>>>(partial, out, NBLK);
}